// Round 11
// baseline (1196.837 us; speedup 1.0000x reference)
//
#include <hip/hip_runtime.h>
#include <hip/hip_bf16.h>

typedef __attribute__((ext_vector_type(8)))  short bf16x8;
typedef __attribute__((ext_vector_type(16))) float f32x16;
typedef __attribute__((ext_vector_type(4)))  float f32x4;

#define NN 50000
#define EE 800000
#define HH 128
#define KK 320   /* 2H + B */
#define NEG 0.01f
#define TROWS 32
#define NT2 (EE / TROWS)    /* 25000 tiles */
#define NBLK 768            /* 256 CU x 3 resident blocks */
#define NSB 196

#define FEATB_BYTES ((size_t)NN * HH * 2)   /* 12.8 MB bf16 feat */
#define PERM_BYTES  ((size_t)EE * 4)        /* 3.2 MB            */

#define GLOAD_LDS(gp, lp) \
    __builtin_amdgcn_global_load_lds( \
        (const __attribute__((address_space(1))) void*)(gp), \
        (__attribute__((address_space(3))) void*)(lp), 16, 0, 0)

__device__ __forceinline__ int pack2(float a, float b) {
    unsigned short lo = __builtin_bit_cast(unsigned short, __float2bfloat16(a));
    unsigned short hi = __builtin_bit_cast(unsigned short, __float2bfloat16(b));
    return (int)((unsigned)lo | ((unsigned)hi << 16));
}

// ---------- feat f32->bf16 + dst histogram (800k threads, exact) ----------
__global__ __launch_bounds__(256) void cvt_hist_kernel(const float* __restrict__ feat,
                                                       ushort* __restrict__ featb,
                                                       const int* __restrict__ dst,
                                                       unsigned* __restrict__ cnt)
{
    const int t = blockIdx.x * 256 + threadIdx.x;
    const float* p = feat + (long long)t * 8;
    f32x4 v0 = *(const f32x4*)p;
    f32x4 v1 = *(const f32x4*)(p + 4);
    int4 h;
    h.x = pack2(v0[0], v0[1]); h.y = pack2(v0[2], v0[3]);
    h.z = pack2(v1[0], v1[1]); h.w = pack2(v1[2], v1[3]);
    *(int4*)(featb + (long long)t * 8) = h;
    atomicAdd(&cnt[dst[t]], 1u);
}

// ---------- CSR scan / perm ----------
__global__ __launch_bounds__(256) void scan1_kernel(const unsigned* __restrict__ cnt,
                                                    unsigned* __restrict__ base,
                                                    unsigned* __restrict__ bsum)
{
    __shared__ unsigned s[256];
    const int tid = threadIdx.x;
    const int g = blockIdx.x * 256 + tid;
    unsigned v = (g < NN) ? cnt[g] : 0u;
    s[tid] = v; __syncthreads();
    #pragma unroll
    for (int o = 1; o < 256; o <<= 1) {
        unsigned t = (tid >= o) ? s[tid - o] : 0u;
        __syncthreads();
        if (tid >= o) s[tid] += t;
        __syncthreads();
    }
    if (g < NN) base[g] = s[tid] - v;
    if (tid == 255) bsum[blockIdx.x] = s[255];
}

__global__ __launch_bounds__(256) void scan2_kernel(unsigned* __restrict__ bsum)
{
    __shared__ unsigned s[256];
    const int tid = threadIdx.x;
    unsigned v = (tid < NSB) ? bsum[tid] : 0u;
    s[tid] = v; __syncthreads();
    #pragma unroll
    for (int o = 1; o < 256; o <<= 1) {
        unsigned t = (tid >= o) ? s[tid - o] : 0u;
        __syncthreads();
        if (tid >= o) s[tid] += t;
        __syncthreads();
    }
    if (tid < NSB) bsum[tid] = s[tid] - v;
}

__global__ __launch_bounds__(256) void scan3_kernel(unsigned* __restrict__ base,
                                                    const unsigned* __restrict__ bsum)
{
    const int g = blockIdx.x * 256 + threadIdx.x;
    if (g < NN) base[g] += bsum[blockIdx.x];
}

__global__ __launch_bounds__(256) void permbuild_kernel(const int* __restrict__ dst,
                                                        const unsigned* __restrict__ base,
                                                        unsigned* __restrict__ cursor,
                                                        int* __restrict__ perm)
{
    const int e = blockIdx.x * 256 + threadIdx.x;
    const int d = dst[e];
    const unsigned rank = atomicAdd(&cursor[d], 1u);
    perm[base[d] + rank] = e;
}

// ---------- main: dst-sorted 32-edge tiles, global_load_lds async pipeline ----------
// LDS tile chunk-major: [40 chunks][32 rows] x 16B; chunk c of row = bytes
// [c*16, c*16+16) of the 640B logical row [src feat | dst feat | gdf bf16].
// A-read for k-step k, half kh: chunk 2k+kh, row = lane&31 (one ds_read_b128).
// Staging: wave w issues 4 global_load_lds (feat chunks w*8..w*8+7, per-lane
// gather addr, lane-linear LDS dest) + per-thread gdf f32->bf16 reg path.
// vmcnt(21) = 2 gdf + 3 idx + 16 atomics issued after the 4 lds-loads:
// stage loads retired at barrier, atomics NEVER drained.
__global__ __launch_bounds__(256, 3) void fused_async_kernel(
    const ushort* __restrict__ featb, const float* __restrict__ gdf,
    const float*  __restrict__ W,     const float* __restrict__ bias,
    const int*    __restrict__ src,   const int*   __restrict__ dst,
    const int*    __restrict__ perm,  float* __restrict__ out)
{
    __shared__ char lds[2][40 * 32 * 16];   // 2 x 20480B
    __shared__ int  dsts[2][TROWS];

    const int tid  = threadIdx.x;
    const int lane = tid & 63;
    const int wid  = tid >> 6;
    const int col  = wid * 32 + (lane & 31);
    const int khalf = lane >> 5;
    const int row  = lane & 31;

    // ---- W fragments (f32 -> bf16, loaded once) ----
    bf16x8 Wb[20];
    {
        const float* wrow = W + col * KK + khalf * 8;
        #pragma unroll
        for (int k = 0; k < 20; k++) {
            f32x4 x0 = *(const f32x4*)(wrow + k * 16);
            f32x4 x1 = *(const f32x4*)(wrow + k * 16 + 4);
            union { bf16x8 v; int u[4]; } t;
            t.u[0] = pack2(x0[0], x0[1]); t.u[1] = pack2(x0[2], x0[3]);
            t.u[2] = pack2(x1[0], x1[1]); t.u[3] = pack2(x1[2], x1[3]);
            Wb[k] = t.v;
        }
    }
    const float bv = bias[col];

    // ---- contiguous chunk of sorted tiles, XCD-sliced ----
    const int xcd = blockIdx.x & 7, wI = blockIdx.x >> 3;
    const int cid = xcd * (NBLK / 8) + wI;
    const int qc  = NT2 / NBLK;
    const int rem = NT2 % NBLK;
    const int t0  = cid * qc + (cid < rem ? cid : rem);
    const int len = qc + (cid < rem ? 1 : 0);
    const int tEnd = t0 + len;

    // ---- prologue: stage tile t0 into buf0 ----
    {
        const int e0 = perm[(long long)t0 * TROWS + row];
        const int s0 = src[e0], d0 = dst[e0];
        #pragma unroll
        for (int i = 0; i < 4; i++) {
            const int cb = wid * 8 + i * 2;
            const int c  = cb + khalf;
            const ushort* g = (c < 16) ? featb + (size_t)s0 * HH + c * 8
                                       : featb + (size_t)d0 * HH + (c - 16) * 8;
            GLOAD_LDS(g, &lds[0][cb * 512]);
        }
        const float* ge = gdf + (size_t)e0 * 64 + (wid * 2 + khalf) * 8;
        f32x4 g0 = *(const f32x4*)ge;
        f32x4 g1 = *(const f32x4*)(ge + 4);
        int4 h;
        h.x = pack2(g0[0], g0[1]); h.y = pack2(g0[2], g0[3]);
        h.z = pack2(g1[0], g1[1]); h.w = pack2(g1[2], g1[3]);
        *(int4*)(&lds[0][((32 + wid * 2 + khalf) * 32 + row) * 16]) = h;
        if (wid == 0 && khalf == 0) dsts[0][row] = d0;
    }
    // ---- idx pipeline: (eA,sA,dA) for t0+1, eB for t0+2 ----
    int eA, sA, dA, eB;
    {
        const int tA = (t0 + 1 < tEnd) ? t0 + 1 : t0;
        eA = perm[(long long)tA * TROWS + row];
        sA = src[eA]; dA = dst[eA];
        const int tB = (t0 + 2 < tEnd) ? t0 + 2 : t0;
        eB = perm[(long long)tB * TROWS + row];
    }
    asm volatile("s_waitcnt vmcnt(0) lgkmcnt(0)" ::: "memory");
    __builtin_amdgcn_sched_barrier(0);
    __builtin_amdgcn_s_barrier();
    __builtin_amdgcn_sched_barrier(0);

    int buf = 0;
    for (int t = t0; ; ++t) {
        const bool hasNext = (t + 1 < tEnd);
        f32x4 g0, g1;
        // -- S1: issue feat global_load_lds (4) + gdf f32 loads (2) for t+1 --
        if (hasNext) {
            #pragma unroll
            for (int i = 0; i < 4; i++) {
                const int cb = wid * 8 + i * 2;
                const int c  = cb + khalf;
                const ushort* g = (c < 16) ? featb + (size_t)sA * HH + c * 8
                                           : featb + (size_t)dA * HH + (c - 16) * 8;
                GLOAD_LDS(g, &lds[buf ^ 1][cb * 512]);
            }
            const float* ge = gdf + (size_t)eA * 64 + (wid * 2 + khalf) * 8;
            g0 = *(const f32x4*)ge;
            g1 = *(const f32x4*)(ge + 4);
            if (wid == 0 && khalf == 0) dsts[buf ^ 1][row] = dA;
        }
        __builtin_amdgcn_sched_barrier(0);
        // -- S2: idx loads for t+2 / t+3 (values needed next iteration) --
        int sB = sA, dB = dA, eC = eB;
        if (hasNext) {
            sB = src[eB]; dB = dst[eB];
            const int tC = (t + 3 < tEnd) ? t + 3 : t0;
            eC = perm[(long long)tC * TROWS + row];
        }
        __builtin_amdgcn_sched_barrier(0);

        // -- S3: MFMA(t): 20 x { ds_read_b128 + mfma } --
        f32x16 acc = {};
        #pragma unroll
        for (int k = 0; k < 20; k++) {
            bf16x8 a = *(const bf16x8*)(&lds[buf][((2 * k + khalf) * 32 + row) * 16]);
            acc = __builtin_amdgcn_mfma_f32_32x32x16_bf16(a, Wb[k], acc, 0, 0, 0);
        }

        __builtin_amdgcn_sched_barrier(0);
        // -- S4: epilogue(t): gate + exactly 16 f32 atomics (compiler-visible) --
        #pragma unroll
        for (int g = 0; g < 4; g++) {
            const int4 dn4 = *(const int4*)(&dsts[buf][g * 8 + khalf * 4]);
            const int dd[4] = { dn4.x, dn4.y, dn4.z, dn4.w };
            #pragma unroll
            for (int j = 0; j < 4; j++) {
                const float z  = acc[g * 4 + j] + bv;
                const float lr = z > 0.f ? z : NEG * z;
                const float m  = lr / (1.f + __expf(-z));
                unsafeAtomicAdd(out + (size_t)dd[j] * HH + col, m);
            }
        }
        __builtin_amdgcn_sched_barrier(0);

        if (!hasNext) break;
        // -- S5: gdf pack + ds_write (auto counted wait for g0/g1) --
        {
            int4 h;
            h.x = pack2(g0[0], g0[1]); h.y = pack2(g0[2], g0[3]);
            h.z = pack2(g1[0], g1[1]); h.w = pack2(g1[2], g1[3]);
            *(int4*)(&lds[buf ^ 1][((32 + wid * 2 + khalf) * 32 + row) * 16]) = h;
        }
        __builtin_amdgcn_sched_barrier(0);
        // -- S6: counted wait (stage retired; atomics stay in flight) + barrier --
        asm volatile("s_waitcnt vmcnt(21) lgkmcnt(0)" ::: "memory");
        __builtin_amdgcn_sched_barrier(0);
        __builtin_amdgcn_s_barrier();
        __builtin_amdgcn_sched_barrier(0);
        eA = eB; sA = sB; dA = dB; eB = eC;
        buf ^= 1;
    }
}

// ---------- fallback (small ws): f32 atomics straight into out ----------
__global__ __launch_bounds__(256) void fused_fallback_kernel(
    const float* __restrict__ feat, const float* __restrict__ gdf,
    const float* __restrict__ W,    const float* __restrict__ bias,
    const int*   __restrict__ src,  const int*   __restrict__ dst,
    float* __restrict__ out)
{
    __shared__ int4 lds4[64 * 40];
    __shared__ int  dsts[64];
    char* lds = (char*)lds4;
    const int tid = threadIdx.x, lane = tid & 63, wid = tid >> 6;
    const int col = wid * 32 + (lane & 31), khalf = lane >> 5;
    const int r = tid >> 2, q = tid & 3;
    const long long ebase = (long long)blockIdx.x * 64;

    bf16x8 Wb[20];
    {
        const float* wrow = W + col * KK + khalf * 8;
        #pragma unroll
        for (int k = 0; k < 20; k++) {
            f32x4 x0 = *(const f32x4*)(wrow + k * 16);
            f32x4 x1 = *(const f32x4*)(wrow + k * 16 + 4);
            union { bf16x8 v; int u[4]; } t;
            t.u[0] = pack2(x0[0], x0[1]); t.u[1] = pack2(x0[2], x0[3]);
            t.u[2] = pack2(x1[0], x1[1]); t.u[3] = pack2(x1[2], x1[3]);
            Wb[k] = t.v;
        }
    }
    const int s = src[ebase + r], d = dst[ebase + r];
    if (q == 0) dsts[r] = d;
    {
        const float* fs = feat + (long long)s * HH;
        const float* fd = feat + (long long)d * HH;
        const float* ge = gdf + (ebase + r) * 64;
        #pragma unroll
        for (int i = 0; i < 10; i++) {
            const int c = q + i * 4;
            const float* p = (c < 16) ? (fs + c * 8)
                           : (c < 32) ? (fd + (c - 16) * 8)
                                      : (ge + (c - 32) * 8);
            f32x4 v0 = *(const f32x4*)p;
            f32x4 v1 = *(const f32x4*)(p + 4);
            int4 h;
            h.x = pack2(v0[0], v0[1]); h.y = pack2(v0[2], v0[3]);
            h.z = pack2(v1[0], v1[1]); h.w = pack2(v1[2], v1[3]);
            *(int4*)(lds + r * 640 + ((c * 16) ^ ((r & 7) << 4))) = h;
        }
    }
    __syncthreads();
    f32x16 acc0 = {}; f32x16 acc1 = {};
    const int arow = lane & 31, xa = (arow & 7) << 4;
    #pragma unroll
    for (int k = 0; k < 20; k++) {
        const int kb = k * 32 + khalf * 16;
        bf16x8 a0 = *(const bf16x8*)(lds + arow * 640 + (kb ^ xa));
        bf16x8 a1 = *(const bf16x8*)(lds + (arow + 32) * 640 + (kb ^ xa));
        acc0 = __builtin_amdgcn_mfma_f32_32x32x16_bf16(a0, Wb[k], acc0, 0, 0, 0);
        acc1 = __builtin_amdgcn_mfma_f32_32x32x16_bf16(a1, Wb[k], acc1, 0, 0, 0);
    }
    const float bv = bias[col];
    #pragma unroll
    for (int rt = 0; rt < 2; rt++) {
        const f32x16 A = rt ? acc1 : acc0;
        #pragma unroll
        for (int g = 0; g < 4; g++) {
            #pragma unroll
            for (int j = 0; j < 4; j++) {
                const int reg = g * 4 + j;
                const int rw = j + g * 8 + khalf * 4;
                const float z  = A[reg] + bv;
                const float lr = z > 0.f ? z : NEG * z;
                const float sgm = 1.f / (1.f + __expf(-z));
                unsafeAtomicAdd(out + (long long)dsts[rt * 32 + rw] * HH + col, lr * sgm);
            }
        }
    }
}

extern "C" void kernel_launch(void* const* d_in, const int* in_sizes, int n_in,
                              void* d_out, int out_size, void* d_ws, size_t ws_size,
                              hipStream_t stream) {
    const float* feat = (const float*)d_in[0];
    const float* gdf  = (const float*)d_in[1];
    const float* W    = (const float*)d_in[2];
    const float* bias = (const float*)d_in[3];
    const int*   src  = (const int*)d_in[4];
    const int*   dst  = (const int*)d_in[5];
    float* out = (float*)d_out;

    char* wsb = (char*)d_ws;
    ushort*   featb  = (ushort*)wsb;
    int*      perm   = (int*)(wsb + FEATB_BYTES);
    unsigned* cnt    = (unsigned*)(wsb + FEATB_BYTES + PERM_BYTES);
    unsigned* cursor = cnt + 50176;
    unsigned* bsum   = cursor + 50176;           // 1024 entries
    unsigned* base   = bsum + 1024;
    const size_t fullBytes = FEATB_BYTES + PERM_BYTES + (3 * 50176 + 1024) * 4;

    if (ws_size >= fullBytes) {
        (void)hipMemsetAsync(out, 0, (size_t)out_size * sizeof(float), stream);
        (void)hipMemsetAsync(cnt, 0, (2 * 50176 + 1024) * 4, stream);  // cnt+cursor+bsum
        cvt_hist_kernel<<<NN * HH / 8 / 256, 256, 0, stream>>>(feat, featb, dst, cnt);
        scan1_kernel<<<NSB, 256, 0, stream>>>(cnt, base, bsum);
        scan2_kernel<<<1, 256, 0, stream>>>(bsum);
        scan3_kernel<<<NSB, 256, 0, stream>>>(base, bsum);
        permbuild_kernel<<<EE / 256, 256, 0, stream>>>(dst, base, cursor, perm);
        fused_async_kernel<<<NBLK, 256, 0, stream>>>(featb, gdf, W, bias,
                                                     src, dst, perm, out);
    } else {
        (void)hipMemsetAsync(out, 0, (size_t)out_size * sizeof(float), stream);
        fused_fallback_kernel<<<EE / 64, 256, 0, stream>>>(feat, gdf, W, bias,
                                                           src, dst, out);
    }
}